// Round 1
// baseline (3323.447 us; speedup 1.0000x reference)
//
#include <hip/hip_runtime.h>
#include <math.h>

// Problem dims (fixed by reference): B=256, T=1000, D=700, H=200, O=35
// M = B*T = 256000, K = D = 700, N = H = 200
//
// Pipeline:
//   1) gemm_in : i_all[m,n] = x[m,:] . W_in[n,:] + b_in[n]   (fp32, VALU-bound)
//   2) lif_scan: per (b,h) leaky-integrate-fire over t, spike counts
//   3) out_gemm: out[b,o] = counts[b,:] . W_out[o,:] + b_out[o]

#define TILE_M 256
#define TILE_N 40
#define TILE_K 20
#define GEMM_THREADS 320  // 5 waves; each wave owns an 8-wide n-strip

__global__ __launch_bounds__(GEMM_THREADS) void gemm_in(
    const float* __restrict__ x, const float* __restrict__ W,
    const float* __restrict__ b_in, float* __restrict__ i_all) {
  // LDS layouts: As[k][m] (m-contiguous), Ws[k][n] (n-contiguous)
  __shared__ __align__(16) float As[TILE_K * TILE_M];
  __shared__ __align__(16) float Ws[TILE_K * TILE_N];

  const int tid = threadIdx.x;
  const int wave = tid >> 6;   // 0..4 -> n-strip
  const int lane = tid & 63;   // rows 4*lane..4*lane+3
  const long m0 = (long)blockIdx.x * TILE_M;
  const int n0 = blockIdx.y * TILE_N;

  float acc[4][8];
#pragma unroll
  for (int mi = 0; mi < 4; ++mi)
#pragma unroll
    for (int ni = 0; ni < 8; ++ni) acc[mi][ni] = 0.0f;

  for (int kt = 0; kt < 700; kt += TILE_K) {
    __syncthreads();  // protect LDS from previous iteration's readers
    // Stage A tile: 256 rows x 20 k = 1280 float4 loads, j = c*320+tid
    // row = j&255 (conflict-free LDS writes), kq = j>>8
#pragma unroll
    for (int c = 0; c < 4; ++c) {
      const int j = c * GEMM_THREADS + tid;
      const int row = j & 255;
      const int kq = j >> 8;
      const float4 v =
          *(const float4*)(x + (m0 + row) * 700 + kt + kq * 4);
      As[(kq * 4 + 0) * TILE_M + row] = v.x;
      As[(kq * 4 + 1) * TILE_M + row] = v.y;
      As[(kq * 4 + 2) * TILE_M + row] = v.z;
      As[(kq * 4 + 3) * TILE_M + row] = v.w;
    }
    // Stage W tile: 40 rows x 20 k = 200 float4 loads
    if (tid < 200) {
      const int row = tid % 40;
      const int kq = tid / 40;
      const float4 v =
          *(const float4*)(W + (long)(n0 + row) * 700 + kt + kq * 4);
      Ws[(kq * 4 + 0) * TILE_N + row] = v.x;
      Ws[(kq * 4 + 1) * TILE_N + row] = v.y;
      Ws[(kq * 4 + 2) * TILE_N + row] = v.z;
      Ws[(kq * 4 + 3) * TILE_N + row] = v.w;
    }
    __syncthreads();

    // Per-tile chunk accumulator (reduces fp32 summation error ~3x)
    float at[4][8];
#pragma unroll
    for (int mi = 0; mi < 4; ++mi)
#pragma unroll
      for (int ni = 0; ni < 8; ++ni) at[mi][ni] = 0.0f;

#pragma unroll 4
    for (int kk = 0; kk < TILE_K; ++kk) {
      const float4 a = *(const float4*)(As + kk * TILE_M + lane * 4);
      const float4 w0 = *(const float4*)(Ws + kk * TILE_N + wave * 8);
      const float4 w1 = *(const float4*)(Ws + kk * TILE_N + wave * 8 + 4);
      const float av[4] = {a.x, a.y, a.z, a.w};
      const float wv[8] = {w0.x, w0.y, w0.z, w0.w, w1.x, w1.y, w1.z, w1.w};
#pragma unroll
      for (int mi = 0; mi < 4; ++mi)
#pragma unroll
        for (int ni = 0; ni < 8; ++ni) at[mi][ni] += av[mi] * wv[ni];
    }
#pragma unroll
    for (int mi = 0; mi < 4; ++mi)
#pragma unroll
      for (int ni = 0; ni < 8; ++ni) acc[mi][ni] += at[mi][ni];
  }

  // Epilogue: add bias, store 2 float4 per row
  float bv[8];
#pragma unroll
  for (int ni = 0; ni < 8; ++ni) bv[ni] = b_in[n0 + wave * 8 + ni];
#pragma unroll
  for (int mi = 0; mi < 4; ++mi) {
    const long m = m0 + lane * 4 + mi;
    float4 o0, o1;
    o0.x = acc[mi][0] + bv[0];
    o0.y = acc[mi][1] + bv[1];
    o0.z = acc[mi][2] + bv[2];
    o0.w = acc[mi][3] + bv[3];
    o1.x = acc[mi][4] + bv[4];
    o1.y = acc[mi][5] + bv[5];
    o1.z = acc[mi][6] + bv[6];
    o1.w = acc[mi][7] + bv[7];
    *(float4*)(i_all + m * 200 + n0 + wave * 8) = o0;
    *(float4*)(i_all + m * 200 + n0 + wave * 8 + 4) = o1;
  }
}

// One thread per (b,h). 200 blocks x 256 threads = 51200 exactly.
__global__ __launch_bounds__(256) void lif_scan(
    const float* __restrict__ i_all, const float* __restrict__ tau_p,
    float* __restrict__ counts) {
  const int idx = blockIdx.x * 256 + threadIdx.x;
  const int b = idx / 200;
  const int h = idx - b * 200;
  const float tau = tau_p[0];
  // Mirror numpy float32: sigmoid via expf, no fused ops in the scan
  const float alpha = 1.0f / (1.0f + expf(-tau));
  const float om = 1.0f - alpha;
  const float* p = i_all + (long)b * 200000 + h;
  float v = 0.0f;
  float cnt = 0.0f;
  for (int t0 = 0; t0 < 1000; t0 += 20) {
    float buf[20];
#pragma unroll
    for (int j = 0; j < 20; ++j) buf[j] = p[(long)(t0 + j) * 200];
#pragma unroll
    for (int j = 0; j < 20; ++j) {
      // v = alpha*v + (1-alpha)*i  -- exact np rounding (no FMA contraction)
      const float v1 = __fadd_rn(__fmul_rn(alpha, v), __fmul_rn(om, buf[j]));
      const float s = (v1 >= 1.0f) ? 1.0f : 0.0f;
      v = v1 - s;
      cnt += s;
    }
  }
  counts[idx] = cnt;
}

__global__ __launch_bounds__(64) void out_gemm(
    const float* __restrict__ counts, const float* __restrict__ W_out,
    const float* __restrict__ b_out, float* __restrict__ out) {
  const int b = blockIdx.x;
  const int o = threadIdx.x;
  if (o >= 35) return;
  const float* c = counts + b * 200;
  const float* w = W_out + o * 200;
  float s = 0.0f;
#pragma unroll 8
  for (int h = 0; h < 200; ++h) s += c[h] * w[h];
  out[b * 35 + o] = s + b_out[o];
}

extern "C" void kernel_launch(void* const* d_in, const int* in_sizes, int n_in,
                              void* d_out, int out_size, void* d_ws,
                              size_t ws_size, hipStream_t stream) {
  const float* x = (const float*)d_in[0];      // (256,1000,700)
  const float* W_in = (const float*)d_in[1];   // (200,700)
  const float* b_in = (const float*)d_in[2];   // (200,)
  const float* W_out = (const float*)d_in[3];  // (35,200)
  const float* b_out = (const float*)d_in[4];  // (35,)
  const float* tau = (const float*)d_in[5];    // scalar
  float* out = (float*)d_out;                  // (256,35) fp32

  float* i_all = (float*)d_ws;  // 256000*200 floats = 204.8 MB
  float* counts = (float*)((char*)d_ws + (size_t)256000 * 200 * sizeof(float));

  dim3 g1(1000, 5);
  gemm_in<<<g1, dim3(GEMM_THREADS), 0, stream>>>(x, W_in, b_in, i_all);
  lif_scan<<<200, 256, 0, stream>>>(i_all, tau, counts);
  out_gemm<<<256, 64, 0, stream>>>(counts, W_out, b_out, out);
}